// Round 13
// baseline (424.371 us; speedup 1.0000x reference)
//
#include <hip/hip_runtime.h>
#include <stdint.h>
#include <math.h>

typedef float  f32x4  __attribute__((ext_vector_type(4)));
typedef __bf16 bf16x8 __attribute__((ext_vector_type(8)));
typedef __bf16 bf16x4 __attribute__((ext_vector_type(4)));

// async global->LDS, 16B per lane. LDS side must be wave-uniform base + lane*16.
__device__ __forceinline__ void gl_lds16(const void* g, void* l) {
  __builtin_amdgcn_global_load_lds(
      (__attribute__((address_space(1))) void*)(uintptr_t)g,
      (__attribute__((address_space(3))) void*)l, 16, 0, 0);
}

// ---------------- cast fp32 -> bf16, x4 vectorized ----------------
__global__ __launch_bounds__(256) void k_cast(const float* __restrict__ in,
                                              __bf16* __restrict__ out, int n4) {
  int i = blockIdx.x * 256 + threadIdx.x;
  if (i >= n4) return;
  f32x4 v = ((const f32x4*)in)[i];
  ((bf16x4*)out)[i] = __builtin_convertvector(v, bf16x4);
}

// ---------------- both weight transposes in one kernel ----------------
// QKV weight rows are reordered on output: original col n = h*384 + which*128 + d
// -> row n' = which*2048 + h*128 + d, so 256-wide GEMM n-tiles are pure Q/K/V.
__global__ __launch_bounds__(256) void k_transpose2(const float* __restrict__ inA,
                                                    __bf16* __restrict__ outA,
                                                    const float* __restrict__ inB,
                                                    __bf16* __restrict__ outB) {
  __shared__ float tile[32][33];
  int bx = blockIdx.x;
  const float* in; __bf16* out; int N, n0, nout;
  if (bx < 192) {
    in = inA; out = outA; N = 6144; n0 = bx * 32;
    int h = n0 / 384, rr = n0 - h * 384;
    int which = rr >> 7, d0 = rr & 127;     // 32-row block never crosses a 128-boundary
    nout = which * 2048 + h * 128 + d0;
  } else {
    in = inB; out = outB; N = 2048; n0 = (bx - 192) * 32; nout = n0;
  }
  const int K = 2048;
  int k0 = blockIdx.y * 32;
  int tx = threadIdx.x & 31, ty = threadIdx.x >> 5;
#pragma unroll
  for (int i = 0; i < 32; i += 8)
    tile[ty + i][tx] = in[(size_t)(k0 + ty + i) * N + n0 + tx];
  __syncthreads();
#pragma unroll
  for (int i = 0; i < 32; i += 8)
    out[(size_t)(nout + ty + i) * K + k0 + tx] = (__bf16)tile[tx][ty + i];
}

// ---------------- shared GEMM core: BM=128 x BN=256, BK=64, 8 waves ----------------
// 3-slot LDS ring, counted vmcnt(6), raw s_barrier, fragment-register
// double-buffering (ds_reads for phase p+1 issue before the MFMAs of phase p).
__device__ __forceinline__ void gemm_core(
    const char* gA, const char* gB, __bf16* smem,
    int wr, int wc, int quad, int l16, int x7, int tthr,
    f32x4 acc[4][4]) {
  int srcA[2], ldsA[2], srcB[4], ldsB[4];
#pragma unroll
  for (int i = 0; i < 2; ++i) {
    int L = i * 512 + tthr;
    int row = L >> 3, sc = L & 7, c = sc ^ (row & 7);
    srcA[i] = row * 4096 + c * 16; ldsA[i] = L * 16;
  }
#pragma unroll
  for (int i = 0; i < 4; ++i) {
    int L = i * 512 + tthr;
    int row = L >> 3, sc = L & 7, c = sc ^ (row & 7);
    srcB[i] = row * 4096 + c * 16; ldsB[i] = L * 16;
  }

  // prologue: stage K-tiles 0 and 1 (6 loads/thread each)
#pragma unroll
  for (int tt = 0; tt < 2; ++tt) {
    int kb = tt * 128;
    char* lA = (char*)smem + tt * 49152;
    char* lB = lA + 16384;
    gl_lds16(gA + srcA[0] + kb, lA + ldsA[0]);
    gl_lds16(gA + srcA[1] + kb, lA + ldsA[1]);
#pragma unroll
    for (int i = 0; i < 4; ++i) gl_lds16(gB + srcB[i] + kb, lB + ldsB[i]);
  }
  asm volatile("s_waitcnt vmcnt(6)" ::: "memory");   // own tile-0 loads landed
  __builtin_amdgcn_s_barrier();                       // all waves' tile-0 landed

  int cs0 = (quad ^ x7) * 8;          // k-slot 0 column select
  int cs1 = ((4 | quad) ^ x7) * 8;    // k-slot 1 column select
  int rowA = (wr * 64 + l16) * 64;    // frag row bases (elems)
  int rowB = (wc * 64 + l16) * 64;

  bf16x8 afA[4], bfA[4], afB[4], bfB[4];
  // preload frags for tile 0, k-slot 0
#pragma unroll
  for (int mt = 0; mt < 4; ++mt) afA[mt] = *(const bf16x8*)(smem + rowA + mt * 1024 + cs0);
#pragma unroll
  for (int nt = 0; nt < 4; ++nt) bfA[nt] = *(const bf16x8*)(smem + 8192 + rowB + nt * 1024 + cs0);

  int slot = 0;
  for (int t = 0; t < 32; ++t) {
    int slot1 = slot + 1; if (slot1 >= 3) slot1 -= 3;
    int slot2 = slot + 2; if (slot2 >= 3) slot2 -= 3;
    const __bf16* sAs  = smem + slot * 24576;
    const __bf16* sBs  = sAs + 8192;
    const __bf16* sAs1 = smem + slot1 * 24576;
    const __bf16* sBs1 = sAs1 + 8192;
    char* lA = (char*)smem + slot2 * 49152;
    char* lB = lA + 16384;
    int kb = (t + 2) * 128;
    bool pf = (t < 30);

    // ---- phase k=0: prefetch k=1 frags, stage group 0, MFMA k=0 ----
    if (pf) {
      gl_lds16(gA + srcA[0] + kb, lA + ldsA[0]);
      gl_lds16(gA + srcA[1] + kb, lA + ldsA[1]);
      gl_lds16(gB + srcB[0] + kb, lB + ldsB[0]);
    }
#pragma unroll
    for (int mt = 0; mt < 4; ++mt) afB[mt] = *(const bf16x8*)(sAs + rowA + mt * 1024 + cs1);
#pragma unroll
    for (int nt = 0; nt < 4; ++nt) bfB[nt] = *(const bf16x8*)(sBs + rowB + nt * 1024 + cs1);
    __builtin_amdgcn_s_setprio(1);
#pragma unroll
    for (int mt = 0; mt < 4; ++mt)
#pragma unroll
      for (int nt = 0; nt < 4; ++nt)
        acc[mt][nt] = __builtin_amdgcn_mfma_f32_16x16x32_bf16(afA[mt], bfA[nt], acc[mt][nt], 0, 0, 0);
    __builtin_amdgcn_s_setprio(0);

    // ---- phase k=1: stage group 1, vmcnt+barrier, prefetch next-tile k=0 frags, MFMA k=1 ----
    if (pf) {
      gl_lds16(gB + srcB[1] + kb, lB + ldsB[1]);
      gl_lds16(gB + srcB[2] + kb, lB + ldsB[2]);
      gl_lds16(gB + srcB[3] + kb, lB + ldsB[3]);
    }
    if (pf) asm volatile("s_waitcnt vmcnt(6)" ::: "memory");   // tile t+1 fully landed (own)
    else    asm volatile("s_waitcnt vmcnt(0)" ::: "memory");   // pipeline drain
    __builtin_amdgcn_s_barrier();                               // all waves: t+1 landed; t-1 reads done
    if (t < 31) {
#pragma unroll
      for (int mt = 0; mt < 4; ++mt) afA[mt] = *(const bf16x8*)(sAs1 + rowA + mt * 1024 + cs0);
#pragma unroll
      for (int nt = 0; nt < 4; ++nt) bfA[nt] = *(const bf16x8*)(sBs1 + rowB + nt * 1024 + cs0);
    }
    __builtin_amdgcn_s_setprio(1);
#pragma unroll
    for (int mt = 0; mt < 4; ++mt)
#pragma unroll
      for (int nt = 0; nt < 4; ++nt)
        acc[mt][nt] = __builtin_amdgcn_mfma_f32_16x16x32_bf16(afB[mt], bfB[nt], acc[mt][nt], 0, 0, 0);
    __builtin_amdgcn_s_setprio(0);
    __builtin_amdgcn_s_barrier();   // tile boundary: protects slot recycle for staging
    slot = slot1;
  }
}

// ---------------- QKV GEMM + fused RoPE + fused V-transpose ----------------
// n-tiles are 256 wide over reordered weights: which = bx>>3; each wave's 64
// n-cols sit inside one head (h = (bx&7)*2 + (wc>>1), d = (wc&1)*64 + ...).
// XCD-aware decode (round-10 best-measured): each XCD owns a 4-row by-band.
__global__ __launch_bounds__(512, 2) void k_gemm_qkv(
    const __bf16* __restrict__ A, const __bf16* __restrict__ Bt,
    const float* __restrict__ bias,
    __bf16* __restrict__ Qo, __bf16* __restrict__ Ko, __bf16* __restrict__ Vt) {
  __shared__ __bf16 smem[3 * 24576];   // 147456 B
  int t = threadIdx.x;
  int w = t >> 6, lane = t & 63;
  int wr = w >> 2, wc = w & 3;
  int quad = lane >> 4, l16 = lane & 15, x7 = lane & 7;

  int g = (int)blockIdx.x + (int)blockIdx.y * 24;   // 0..767, x-fastest dispatch
  int xcd = g & 7, idx = g >> 3;                    // idx 0..95
  int by = (xcd << 2) | (idx & 3);                  // 4-row band per XCD
  int bx = idx >> 2;                                // 0..23, advances every 4 blocks
  int m0 = by << 7;
  int n0 = bx << 8;

  f32x4 acc[4][4] = {};
  const char* gA = (const char*)(A + (size_t)m0 * 2048);
  const char* gB = (const char*)(Bt + (size_t)n0 * 2048);
  gemm_core(gA, gB, smem, wr, wc, quad, l16, x7, t, acc);

  int which = bx >> 3;
  int h = ((bx & 7) << 1) + (wc >> 1);
  int dbase = (wc & 1) << 6;
  int b2 = m0 >> 11, sbase = m0 & 2047;
  size_t bh = (size_t)(b2 * 16 + h);

  if (which == 2) {
    // V: per-wave LDS transpose (64 d x 64 s, stride 72 for 16B-aligned reads),
    // coalesced 16B stores into Vt [bh][128][2048]. Last core barrier precedes this.
    __bf16* sp = smem + w * 4608;      // 64*72 elems per wave
    const float* bptr = bias + h * 384 + 256 + dbase;
#pragma unroll
    for (int nt = 0; nt < 4; ++nt) {
      float bz = bptr[nt * 16 + l16];
#pragma unroll
      for (int mt = 0; mt < 4; ++mt) {
        bf16x4 v;
#pragma unroll
        for (int r = 0; r < 4; ++r) v[r] = (__bf16)(acc[mt][nt][r] + bz);
        *(bf16x4*)(sp + (nt * 16 + l16) * 72 + mt * 16 + quad * 4) = v;
      }
    }
    asm volatile("s_waitcnt lgkmcnt(0)" ::: "memory");
    int dl = lane >> 3, sseg = lane & 7;
#pragma unroll
    for (int p = 0; p < 8; ++p) {
      int d_local = p * 8 + dl;
      bf16x8 v = *(const bf16x8*)(sp + d_local * 72 + sseg * 8);
      *(bf16x8*)(Vt + (bh * 128 + dbase + d_local) * 2048 + sbase + wr * 64 + sseg * 8) = v;
    }
  } else {
    __bf16* dst = which ? Ko : Qo;
    const float* bptr = bias + h * 384 + which * 128 + dbase;
    float invf = exp2f(-(float)l16 * 0.83048202372184058f);  // 10000^(-l16/16)
#pragma unroll
    for (int mt = 0; mt < 4; ++mt) {
      int m = m0 + wr * 64 + mt * 16 + quad * 4;
#pragma unroll
      for (int nt = 0; nt < 4; ++nt) {
        int d = dbase + nt * 16 + l16;
        float bz = bptr[nt * 16 + l16];
        if (dbase == 0 && nt < 2) {
          if (nt == 0) {  // RoPE pair: this lane holds d=l16 and d=l16+16
            float bz1 = bptr[16 + l16];
#pragma unroll
            for (int r = 0; r < 4; ++r) {
              int s = (m + r) & 2047;
              float sn, cs2;
              __sincosf((float)s * invf, &sn, &cs2);
              float x1 = acc[mt][0][r] + bz;
              float x2 = acc[mt][1][r] + bz1;
              size_t off = (bh * 2048 + s) << 7;
              dst[off + l16]      = (__bf16)(x1 * cs2 - x2 * sn);
              dst[off + 16 + l16] = (__bf16)(x2 * cs2 + x1 * sn);
            }
          }
        } else {
#pragma unroll
          for (int r = 0; r < 4; ++r) {
            int s = (m + r) & 2047;
            dst[(bh * 2048 + s) * 128 + d] = (__bf16)(acc[mt][nt][r] + bz);
          }
        }
      }
    }
  }
}

// ---------------- Out-proj GEMM: attn[4096][2048] bf16 x Bt[2048][2048] bf16 -> f32 ----------------
__global__ __launch_bounds__(512, 2) void k_gemm_out(
    const __bf16* __restrict__ A, const __bf16* __restrict__ Bt,
    const float* __restrict__ bias, float* __restrict__ Out) {
  __shared__ __bf16 smem[3 * 24576];
  int t = threadIdx.x;
  int w = t >> 6, lane = t & 63;
  int wr = w >> 2, wc = w & 3;
  int quad = lane >> 4, l16 = lane & 15, x7 = lane & 7;

  int g = (int)blockIdx.x + (int)blockIdx.y * 8;    // 0..255
  int xcd = g & 7, idx = g >> 3;                    // idx 0..31
  int by = (xcd << 2) | (idx & 3);                  // 4-row band per XCD
  int bx = idx >> 2;                                // 0..7
  int m0 = by << 7;
  int n0 = bx << 8;

  f32x4 acc[4][4] = {};
  const char* gA = (const char*)(A + (size_t)m0 * 2048);
  const char* gB = (const char*)(Bt + (size_t)n0 * 2048);
  gemm_core(gA, gB, smem, wr, wc, quad, l16, x7, t, acc);

#pragma unroll
  for (int mt = 0; mt < 4; ++mt) {
    int m = m0 + wr * 64 + mt * 16 + quad * 4;
#pragma unroll
    for (int nt = 0; nt < 4; ++nt) {
      int n = n0 + wc * 64 + nt * 16 + l16;
      float bz = bias[n];
#pragma unroll
      for (int r = 0; r < 4; ++r)
        Out[(size_t)(m + r) * 2048 + n] = acc[mt][nt][r] + bz;
    }
  }
}

// ---------------- causal flash attention, 128-row KV tiles ----------------
// NEW: software-pipelined staging with counted vmcnt (no per-tile full drain).
// Stage K(j+1) after QK^T releases sK (bar_A); stage V(j+1) after PV releases
// sV (bar_C). vmcnt(8) before PV waits V(j) leaving K(j+1) in flight; vmcnt(8)
// at tile end waits K(j+1) leaving V(j+1) in flight.
__global__ __launch_bounds__(256) void k_attn(const __bf16* __restrict__ Qb,
                                              const __bf16* __restrict__ Kb,
                                              const __bf16* __restrict__ Vt,
                                              __bf16* __restrict__ Ob) {
  __shared__ __bf16 sK[128 * 128];   // [kv][d], swizzled 16B chunks (16/row)
  __shared__ __bf16 sV[144 * 128];   // [d][kv], swizzled; rows 128..143 = 1.0
  __shared__ __bf16 sP[4 * 16 * 72];
  const float SCL = 0.08838834764831845f * 1.4426950408889634f;  // 1/sqrt(128)*log2e
  int t = threadIdx.x, w = t >> 6, lane = t & 63;
  int quad = lane >> 4, l16 = lane & 15;
  int bh = blockIdx.y;
  size_t base = (size_t)bh * (2048 * 128);
  const char* gK = (const char*)(Kb + base);
  const char* gV = (const char*)(Vt + base);
  __bf16* sp = sP + w * (16 * 72);
  int b = bh >> 4, h = bh & 15;

  // ones rows (sV rows 128..143), never touched by staging (it writes rows 0..127)
  for (int i = t; i < 2048; i += 256) sV[128 * 128 + i] = (__bf16)1.0f;
  asm volatile("s_waitcnt lgkmcnt(0)" ::: "memory");

  for (int ph = 0; ph < 2; ++ph) {
    int qt = (ph == 0) ? (int)blockIdx.x : 31 - (int)blockIdx.x;
    int q0 = qt * 64;
    int ntiles = (qt >> 1) + 1;

    bf16x8 aq[4];
    {
      const __bf16* qp = Qb + base + (size_t)(q0 + w * 16 + l16) * 128 + quad * 8;
#pragma unroll
      for (int kc = 0; kc < 4; ++kc) aq[kc] = *(const bf16x8*)(qp + kc * 32);
    }

    f32x4 o[8] = {};
    f32x4 ol = {};
    float mrow[4], alpha[4];
#pragma unroll
    for (int r = 0; r < 4; ++r) mrow[r] = -INFINITY;

    // prologue: stage K(0), V(0); full drain; barrier (previous readers done at bar_C)
#pragma unroll
    for (int i = 0; i < 8; ++i) {
      int L = i * 256 + t, row = L >> 4, sc = L & 15;
      int c = (sc & 8) | ((sc & 7) ^ (row & 7));
      gl_lds16(gK + (size_t)row * 256 + c * 16, (char*)sK + L * 16);
    }
#pragma unroll
    for (int i = 0; i < 8; ++i) {
      int L = i * 256 + t, row = L >> 4, sc = L & 15;
      int c = (sc & 8) | ((sc & 7) ^ (row & 7));
      gl_lds16(gV + (size_t)row * 4096 + c * 16, (char*)sV + L * 16);
    }
    asm volatile("s_waitcnt vmcnt(0)" ::: "memory");
    __builtin_amdgcn_s_barrier();

    for (int j = 0; j < ntiles; ++j) {
      bool more = (j + 1 < ntiles);
      int kvn = (j + 1) << 7;

      // S = Q K^T, pre-scaled into log2 domain (16 q-rows x 128 kv-cols per wave)
      float sv[8][4];
      __builtin_amdgcn_s_setprio(1);
#pragma unroll
      for (int nt = 0; nt < 8; ++nt) {
        f32x4 z = {};
#pragma unroll
        for (int kc = 0; kc < 4; ++kc) {
          int sc = ((kc & 2) << 2) | (((((kc & 1) << 2) | quad)) ^ (l16 & 7));
          bf16x8 bk = *(const bf16x8*)(sK + (nt * 16 + l16) * 128 + sc * 8);
          z = __builtin_amdgcn_mfma_f32_16x16x32_bf16(aq[kc], bk, z, 0, 0, 0);
        }
#pragma unroll
        for (int r = 0; r < 4; ++r) sv[nt][r] = z[r] * SCL;
      }
      __builtin_amdgcn_s_setprio(0);
      asm volatile("s_waitcnt lgkmcnt(0)" ::: "memory");  // sK reads complete
      __builtin_amdgcn_s_barrier();                        // bar_A: sK free
      if (more) {  // stage K(j+1), overlapped with softmax + PV
#pragma unroll
        for (int i = 0; i < 8; ++i) {
          int L = i * 256 + t, row = L >> 4, sc = L & 15;
          int c = (sc & 8) | ((sc & 7) ^ (row & 7));
          gl_lds16(gK + (size_t)(kvn + row) * 256 + c * 16, (char*)sK + L * 16);
        }
      }
      if (j == ntiles - 1) {  // tile containing the diagonal: causal mask
#pragma unroll
        for (int nt = 0; nt < 8; ++nt) {
          int col = (j << 7) + nt * 16 + l16;
#pragma unroll
          for (int r = 0; r < 4; ++r) {
            int row = q0 + w * 16 + quad * 4 + r;
            if (col > row) sv[nt][r] = -1e9f;
          }
        }
      }
      // online softmax (max only; sum via ones-rows MFMA)
#pragma unroll
      for (int r = 0; r < 4; ++r) {
        float mx = sv[0][r];
#pragma unroll
        for (int nt = 1; nt < 8; ++nt) mx = fmaxf(mx, sv[nt][r]);
#pragma unroll
        for (int off = 1; off < 16; off <<= 1) mx = fmaxf(mx, __shfl_xor(mx, off, 64));
        float mnew = fmaxf(mrow[r], mx);
        alpha[r] = exp2f(mrow[r] - mnew);
        mrow[r] = mnew;
#pragma unroll
        for (int nt = 0; nt < 8; ++nt) sv[nt][r] = exp2f(sv[nt][r] - mnew);
      }
      // rescale accumulators once per tile
#pragma unroll
      for (int nt = 0; nt < 8; ++nt)
#pragma unroll
        for (int r = 0; r < 4; ++r) o[nt][r] *= alpha[r];
#pragma unroll
      for (int r = 0; r < 4; ++r) ol[r] *= alpha[r];

      // V(j) landed on all waves (K(j+1)'s 8 loads may stay in flight)
      if (more) asm volatile("s_waitcnt vmcnt(8)" ::: "memory");
      else      asm volatile("s_waitcnt vmcnt(0)" ::: "memory");
      __builtin_amdgcn_s_barrier();                        // bar_B: sV ready

      // PV in two 64-kv halves through wave-private sP
#pragma unroll
      for (int half = 0; half < 2; ++half) {
#pragma unroll
        for (int nt = 0; nt < 4; ++nt)
#pragma unroll
          for (int r = 0; r < 4; ++r)
            sp[(quad * 4 + r) * 72 + nt * 16 + l16] = (__bf16)sv[half * 4 + nt][r];
        asm volatile("s_waitcnt lgkmcnt(0)" ::: "memory");  // writes visible (and prior reads landed)
        __builtin_amdgcn_s_setprio(1);
#pragma unroll
        for (int kc = 0; kc < 2; ++kc) {
          bf16x8 ap = *(const bf16x8*)(sp + l16 * 72 + kc * 32 + quad * 8);
          int sc = (half << 3) | (((kc << 2) | quad) ^ (l16 & 7));
#pragma unroll
          for (int nt = 0; nt < 8; ++nt) {
            bf16x8 bv = *(const bf16x8*)(sV + (nt * 16 + l16) * 128 + sc * 8);
            o[nt] = __builtin_amdgcn_mfma_f32_16x16x32_bf16(ap, bv, o[nt], 0, 0, 0);
          }
          bf16x8 bv1 = *(const bf16x8*)(sV + (128 + l16) * 128 + sc * 8);  // ones
          ol = __builtin_amdgcn_mfma_f32_16x16x32_bf16(ap, bv1, ol, 0, 0, 0);
        }
        __builtin_amdgcn_s_setprio(0);
        asm volatile("s_waitcnt lgkmcnt(0)" ::: "memory");  // reads landed before sP overwrite
      }
      __builtin_amdgcn_s_barrier();                        // bar_C: sV free
      if (more) {  // stage V(j+1); ensure K(j+1) landed before next QK^T
#pragma unroll
        for (int i = 0; i < 8; ++i) {
          int L = i * 256 + t, row = L >> 4, sc = L & 15;
          int c = (sc & 8) | ((sc & 7) ^ (row & 7));
          gl_lds16(gV + (size_t)row * 4096 + kvn * 2 + c * 16, (char*)sV + L * 16);
        }
        asm volatile("s_waitcnt vmcnt(8)" ::: "memory");   // K(j+1) landed
        __builtin_amdgcn_s_barrier();                      // bar_D: sK ready
      }
    }

    // epilogue: O/l -> attn buffer [b][s][h][d] bf16
#pragma unroll
    for (int r = 0; r < 4; ++r) {
      float inv = 1.f / ol[r];
      int srow = q0 + w * 16 + quad * 4 + r;
      __bf16* op = Ob + ((size_t)((b * 2048 + srow) * 16 + h)) * 128;
#pragma unroll
      for (int nt = 0; nt < 8; ++nt)
        op[nt * 16 + l16] = (__bf16)(o[nt][r] * inv);
    }
  }
}

extern "C" void kernel_launch(void* const* d_in, const int* in_sizes, int n_in,
                              void* d_out, int out_size, void* d_ws, size_t ws_size,
                              hipStream_t stream) {
  const float* hs   = (const float*)d_in[0];
  const float* wqkv = (const float*)d_in[2];
  const float* bqkv = (const float*)d_in[3];
  const float* wout = (const float*)d_in[4];
  const float* bout = (const float*)d_in[5];
  float* out = (float*)d_out;

  char* ws = (char*)d_ws;
  __bf16* hsb   = (__bf16*)(ws);                // [4096][2048]; reused as attnb
  __bf16* attnb = (__bf16*)(ws);
  __bf16* wqkvT = (__bf16*)(ws + 16777216);     // [6144][2048], rows reordered [which][h][128]
  __bf16* woutT = (__bf16*)(ws + 41943040);     // [2048][2048]
  __bf16* Qb    = (__bf16*)(ws + 50331648);     // [32][2048][128]
  __bf16* Kb    = (__bf16*)(ws + 67108864);     // [32][2048][128]
  __bf16* Vt    = (__bf16*)(ws + 83886080);     // [32][128][2048] (transposed V)
  // total ws use: 100,663,296 B

  k_cast<<<8192, 256, 0, stream>>>(hs, hsb, 2097152);
  k_transpose2<<<dim3(256, 64), 256, 0, stream>>>(wqkv, wqkvT, wout, woutT);
  k_gemm_qkv<<<dim3(24, 32), 512, 0, stream>>>(hsb, wqkvT, bqkv, Qb, Kb, Vt);
  k_attn<<<dim3(16, 32), 256, 0, stream>>>(Qb, Kb, Vt, attnb);
  k_gemm_out<<<dim3(8, 32), 512, 0, stream>>>(attnb, woutT, bout, out);
}

// Round 14
// 388.007 us; speedup vs baseline: 1.0937x; 1.0937x over previous
//
#include <hip/hip_runtime.h>
#include <stdint.h>
#include <math.h>

typedef float  f32x4  __attribute__((ext_vector_type(4)));
typedef __bf16 bf16x8 __attribute__((ext_vector_type(8)));
typedef __bf16 bf16x4 __attribute__((ext_vector_type(4)));

// async global->LDS, 16B per lane. LDS side must be wave-uniform base + lane*16.
__device__ __forceinline__ void gl_lds16(const void* g, void* l) {
  __builtin_amdgcn_global_load_lds(
      (__attribute__((address_space(1))) void*)(uintptr_t)g,
      (__attribute__((address_space(3))) void*)l, 16, 0, 0);
}

// ---------------- cast fp32 -> bf16, x4 vectorized ----------------
__global__ __launch_bounds__(256) void k_cast(const float* __restrict__ in,
                                              __bf16* __restrict__ out, int n4) {
  int i = blockIdx.x * 256 + threadIdx.x;
  if (i >= n4) return;
  f32x4 v = ((const f32x4*)in)[i];
  ((bf16x4*)out)[i] = __builtin_convertvector(v, bf16x4);
}

// ---------------- both weight transposes in one kernel ----------------
// QKV weight rows are reordered on output: original col n = h*384 + which*128 + d
// -> row n' = which*2048 + h*128 + d, so 256-wide GEMM n-tiles are pure Q/K/V.
__global__ __launch_bounds__(256) void k_transpose2(const float* __restrict__ inA,
                                                    __bf16* __restrict__ outA,
                                                    const float* __restrict__ inB,
                                                    __bf16* __restrict__ outB) {
  __shared__ float tile[32][33];
  int bx = blockIdx.x;
  const float* in; __bf16* out; int N, n0, nout;
  if (bx < 192) {
    in = inA; out = outA; N = 6144; n0 = bx * 32;
    int h = n0 / 384, rr = n0 - h * 384;
    int which = rr >> 7, d0 = rr & 127;     // 32-row block never crosses a 128-boundary
    nout = which * 2048 + h * 128 + d0;
  } else {
    in = inB; out = outB; N = 2048; n0 = (bx - 192) * 32; nout = n0;
  }
  const int K = 2048;
  int k0 = blockIdx.y * 32;
  int tx = threadIdx.x & 31, ty = threadIdx.x >> 5;
#pragma unroll
  for (int i = 0; i < 32; i += 8)
    tile[ty + i][tx] = in[(size_t)(k0 + ty + i) * N + n0 + tx];
  __syncthreads();
#pragma unroll
  for (int i = 0; i < 32; i += 8)
    out[(size_t)(nout + ty + i) * K + k0 + tx] = (__bf16)tile[tx][ty + i];
}

// ---------------- shared GEMM core: BM=128 x BN=256, BK=64, 8 waves ----------------
// 3-slot LDS ring, counted vmcnt(6), raw s_barrier, fragment-register
// double-buffering (ds_reads for phase p+1 issue before the MFMAs of phase p).
__device__ __forceinline__ void gemm_core(
    const char* gA, const char* gB, __bf16* smem,
    int wr, int wc, int quad, int l16, int x7, int tthr,
    f32x4 acc[4][4]) {
  int srcA[2], ldsA[2], srcB[4], ldsB[4];
#pragma unroll
  for (int i = 0; i < 2; ++i) {
    int L = i * 512 + tthr;
    int row = L >> 3, sc = L & 7, c = sc ^ (row & 7);
    srcA[i] = row * 4096 + c * 16; ldsA[i] = L * 16;
  }
#pragma unroll
  for (int i = 0; i < 4; ++i) {
    int L = i * 512 + tthr;
    int row = L >> 3, sc = L & 7, c = sc ^ (row & 7);
    srcB[i] = row * 4096 + c * 16; ldsB[i] = L * 16;
  }

  // prologue: stage K-tiles 0 and 1 (6 loads/thread each)
#pragma unroll
  for (int tt = 0; tt < 2; ++tt) {
    int kb = tt * 128;
    char* lA = (char*)smem + tt * 49152;
    char* lB = lA + 16384;
    gl_lds16(gA + srcA[0] + kb, lA + ldsA[0]);
    gl_lds16(gA + srcA[1] + kb, lA + ldsA[1]);
#pragma unroll
    for (int i = 0; i < 4; ++i) gl_lds16(gB + srcB[i] + kb, lB + ldsB[i]);
  }
  asm volatile("s_waitcnt vmcnt(6)" ::: "memory");   // own tile-0 loads landed
  __builtin_amdgcn_s_barrier();                       // all waves' tile-0 landed

  int cs0 = (quad ^ x7) * 8;          // k-slot 0 column select
  int cs1 = ((4 | quad) ^ x7) * 8;    // k-slot 1 column select
  int rowA = (wr * 64 + l16) * 64;    // frag row bases (elems)
  int rowB = (wc * 64 + l16) * 64;

  bf16x8 afA[4], bfA[4], afB[4], bfB[4];
  // preload frags for tile 0, k-slot 0
#pragma unroll
  for (int mt = 0; mt < 4; ++mt) afA[mt] = *(const bf16x8*)(smem + rowA + mt * 1024 + cs0);
#pragma unroll
  for (int nt = 0; nt < 4; ++nt) bfA[nt] = *(const bf16x8*)(smem + 8192 + rowB + nt * 1024 + cs0);

  int slot = 0;
  for (int t = 0; t < 32; ++t) {
    int slot1 = slot + 1; if (slot1 >= 3) slot1 -= 3;
    int slot2 = slot + 2; if (slot2 >= 3) slot2 -= 3;
    const __bf16* sAs  = smem + slot * 24576;
    const __bf16* sBs  = sAs + 8192;
    const __bf16* sAs1 = smem + slot1 * 24576;
    const __bf16* sBs1 = sAs1 + 8192;
    char* lA = (char*)smem + slot2 * 49152;
    char* lB = lA + 16384;
    int kb = (t + 2) * 128;
    bool pf = (t < 30);

    // ---- phase k=0: prefetch k=1 frags, stage group 0, MFMA k=0 ----
    if (pf) {
      gl_lds16(gA + srcA[0] + kb, lA + ldsA[0]);
      gl_lds16(gA + srcA[1] + kb, lA + ldsA[1]);
      gl_lds16(gB + srcB[0] + kb, lB + ldsB[0]);
    }
#pragma unroll
    for (int mt = 0; mt < 4; ++mt) afB[mt] = *(const bf16x8*)(sAs + rowA + mt * 1024 + cs1);
#pragma unroll
    for (int nt = 0; nt < 4; ++nt) bfB[nt] = *(const bf16x8*)(sBs + rowB + nt * 1024 + cs1);
    __builtin_amdgcn_s_setprio(1);
#pragma unroll
    for (int mt = 0; mt < 4; ++mt)
#pragma unroll
      for (int nt = 0; nt < 4; ++nt)
        acc[mt][nt] = __builtin_amdgcn_mfma_f32_16x16x32_bf16(afA[mt], bfA[nt], acc[mt][nt], 0, 0, 0);
    __builtin_amdgcn_s_setprio(0);

    // ---- phase k=1: stage group 1, vmcnt+barrier, prefetch next-tile k=0 frags, MFMA k=1 ----
    if (pf) {
      gl_lds16(gB + srcB[1] + kb, lB + ldsB[1]);
      gl_lds16(gB + srcB[2] + kb, lB + ldsB[2]);
      gl_lds16(gB + srcB[3] + kb, lB + ldsB[3]);
    }
    if (pf) asm volatile("s_waitcnt vmcnt(6)" ::: "memory");   // tile t+1 fully landed (own)
    else    asm volatile("s_waitcnt vmcnt(0)" ::: "memory");   // pipeline drain
    __builtin_amdgcn_s_barrier();                               // all waves: t+1 landed; t-1 reads done
    if (t < 31) {
#pragma unroll
      for (int mt = 0; mt < 4; ++mt) afA[mt] = *(const bf16x8*)(sAs1 + rowA + mt * 1024 + cs0);
#pragma unroll
      for (int nt = 0; nt < 4; ++nt) bfA[nt] = *(const bf16x8*)(sBs1 + rowB + nt * 1024 + cs0);
    }
    __builtin_amdgcn_s_setprio(1);
#pragma unroll
    for (int mt = 0; mt < 4; ++mt)
#pragma unroll
      for (int nt = 0; nt < 4; ++nt)
        acc[mt][nt] = __builtin_amdgcn_mfma_f32_16x16x32_bf16(afB[mt], bfB[nt], acc[mt][nt], 0, 0, 0);
    __builtin_amdgcn_s_setprio(0);
    __builtin_amdgcn_s_barrier();   // tile boundary: protects slot recycle for staging
    slot = slot1;
  }
}

// ---------------- QKV GEMM + fused RoPE + fused V-transpose ----------------
// n-tiles are 256 wide over reordered weights: which = bx>>3; each wave's 64
// n-cols sit inside one head (h = (bx&7)*2 + (wc>>1), d = (wc&1)*64 + ...).
// XCD-aware decode (best-measured): each XCD owns a 4-row by-band.
__global__ __launch_bounds__(512, 2) void k_gemm_qkv(
    const __bf16* __restrict__ A, const __bf16* __restrict__ Bt,
    const float* __restrict__ bias,
    __bf16* __restrict__ Qo, __bf16* __restrict__ Ko, __bf16* __restrict__ Vt) {
  __shared__ __bf16 smem[3 * 24576];   // 147456 B
  int t = threadIdx.x;
  int w = t >> 6, lane = t & 63;
  int wr = w >> 2, wc = w & 3;
  int quad = lane >> 4, l16 = lane & 15, x7 = lane & 7;

  int g = (int)blockIdx.x + (int)blockIdx.y * 24;   // 0..767, x-fastest dispatch
  int xcd = g & 7, idx = g >> 3;                    // idx 0..95
  int by = (xcd << 2) | (idx & 3);                  // 4-row band per XCD
  int bx = idx >> 2;                                // 0..23, advances every 4 blocks
  int m0 = by << 7;
  int n0 = bx << 8;

  f32x4 acc[4][4] = {};
  const char* gA = (const char*)(A + (size_t)m0 * 2048);
  const char* gB = (const char*)(Bt + (size_t)n0 * 2048);
  gemm_core(gA, gB, smem, wr, wc, quad, l16, x7, t, acc);

  int which = bx >> 3;
  int h = ((bx & 7) << 1) + (wc >> 1);
  int dbase = (wc & 1) << 6;
  int b2 = m0 >> 11, sbase = m0 & 2047;
  size_t bh = (size_t)(b2 * 16 + h);

  if (which == 2) {
    // V: per-wave LDS transpose (64 d x 64 s, stride 72 for 16B-aligned reads),
    // coalesced 16B stores into Vt [bh][128][2048]. Last core barrier precedes this.
    __bf16* sp = smem + w * 4608;      // 64*72 elems per wave
    const float* bptr = bias + h * 384 + 256 + dbase;
#pragma unroll
    for (int nt = 0; nt < 4; ++nt) {
      float bz = bptr[nt * 16 + l16];
#pragma unroll
      for (int mt = 0; mt < 4; ++mt) {
        bf16x4 v;
#pragma unroll
        for (int r = 0; r < 4; ++r) v[r] = (__bf16)(acc[mt][nt][r] + bz);
        *(bf16x4*)(sp + (nt * 16 + l16) * 72 + mt * 16 + quad * 4) = v;
      }
    }
    asm volatile("s_waitcnt lgkmcnt(0)" ::: "memory");
    int dl = lane >> 3, sseg = lane & 7;
#pragma unroll
    for (int p = 0; p < 8; ++p) {
      int d_local = p * 8 + dl;
      bf16x8 v = *(const bf16x8*)(sp + d_local * 72 + sseg * 8);
      *(bf16x8*)(Vt + (bh * 128 + dbase + d_local) * 2048 + sbase + wr * 64 + sseg * 8) = v;
    }
  } else {
    __bf16* dst = which ? Ko : Qo;
    const float* bptr = bias + h * 384 + which * 128 + dbase;
    float invf = exp2f(-(float)l16 * 0.83048202372184058f);  // 10000^(-l16/16)
#pragma unroll
    for (int mt = 0; mt < 4; ++mt) {
      int m = m0 + wr * 64 + mt * 16 + quad * 4;
#pragma unroll
      for (int nt = 0; nt < 4; ++nt) {
        int d = dbase + nt * 16 + l16;
        float bz = bptr[nt * 16 + l16];
        if (dbase == 0 && nt < 2) {
          if (nt == 0) {  // RoPE pair: this lane holds d=l16 and d=l16+16
            float bz1 = bptr[16 + l16];
#pragma unroll
            for (int r = 0; r < 4; ++r) {
              int s = (m + r) & 2047;
              float sn, cs2;
              __sincosf((float)s * invf, &sn, &cs2);
              float x1 = acc[mt][0][r] + bz;
              float x2 = acc[mt][1][r] + bz1;
              size_t off = (bh * 2048 + s) << 7;
              dst[off + l16]      = (__bf16)(x1 * cs2 - x2 * sn);
              dst[off + 16 + l16] = (__bf16)(x2 * cs2 + x1 * sn);
            }
          }
        } else {
#pragma unroll
          for (int r = 0; r < 4; ++r) {
            int s = (m + r) & 2047;
            dst[(bh * 2048 + s) * 128 + d] = (__bf16)(acc[mt][nt][r] + bz);
          }
        }
      }
    }
  }
}

// ---------------- Out-proj GEMM: attn[4096][2048] bf16 x Bt[2048][2048] bf16 -> f32 ----------------
__global__ __launch_bounds__(512, 2) void k_gemm_out(
    const __bf16* __restrict__ A, const __bf16* __restrict__ Bt,
    const float* __restrict__ bias, float* __restrict__ Out) {
  __shared__ __bf16 smem[3 * 24576];
  int t = threadIdx.x;
  int w = t >> 6, lane = t & 63;
  int wr = w >> 2, wc = w & 3;
  int quad = lane >> 4, l16 = lane & 15, x7 = lane & 7;

  int g = (int)blockIdx.x + (int)blockIdx.y * 8;    // 0..255
  int xcd = g & 7, idx = g >> 3;                    // idx 0..31
  int by = (xcd << 2) | (idx & 3);                  // 4-row band per XCD
  int bx = idx >> 2;                                // 0..7
  int m0 = by << 7;
  int n0 = bx << 8;

  f32x4 acc[4][4] = {};
  const char* gA = (const char*)(A + (size_t)m0 * 2048);
  const char* gB = (const char*)(Bt + (size_t)n0 * 2048);
  gemm_core(gA, gB, smem, wr, wc, quad, l16, x7, t, acc);

#pragma unroll
  for (int mt = 0; mt < 4; ++mt) {
    int m = m0 + wr * 64 + mt * 16 + quad * 4;
#pragma unroll
    for (int nt = 0; nt < 4; ++nt) {
      int n = n0 + wc * 64 + nt * 16 + l16;
      float bz = bias[n];
#pragma unroll
      for (int r = 0; r < 4; ++r)
        Out[(size_t)(m + r) * 2048 + n] = acc[mt][nt][r] + bz;
    }
  }
}

// ---------------- causal flash attention, 128-row KV tiles (reverted to best) ----------------
__global__ __launch_bounds__(256) void k_attn(const __bf16* __restrict__ Qb,
                                              const __bf16* __restrict__ Kb,
                                              const __bf16* __restrict__ Vt,
                                              __bf16* __restrict__ Ob) {
  __shared__ __bf16 sK[128 * 128];   // [kv][d], swizzled 16B chunks (16/row)
  __shared__ __bf16 sV[144 * 128];   // [d][kv], swizzled; rows 128..143 = 1.0
  __shared__ __bf16 sP[4 * 16 * 72];
  const float SCL = 0.08838834764831845f * 1.4426950408889634f;  // 1/sqrt(128)*log2e
  int t = threadIdx.x, w = t >> 6, lane = t & 63;
  int quad = lane >> 4, l16 = lane & 15;
  int bh = blockIdx.y;
  size_t base = (size_t)bh * (2048 * 128);
  const char* gK = (const char*)(Kb + base);
  const char* gV = (const char*)(Vt + base);
  __bf16* sp = sP + w * (16 * 72);
  int b = bh >> 4, h = bh & 15;

  // ones rows (sV rows 128..143), never touched by staging
  for (int i = t; i < 2048; i += 256) sV[128 * 128 + i] = (__bf16)1.0f;

  for (int ph = 0; ph < 2; ++ph) {
    int qt = (ph == 0) ? (int)blockIdx.x : 31 - (int)blockIdx.x;
    int q0 = qt * 64;
    int ntiles = (qt >> 1) + 1;

    bf16x8 aq[4];
    {
      const __bf16* qp = Qb + base + (size_t)(q0 + w * 16 + l16) * 128 + quad * 8;
#pragma unroll
      for (int kc = 0; kc < 4; ++kc) aq[kc] = *(const bf16x8*)(qp + kc * 32);
    }

    f32x4 o[8] = {};
    f32x4 ol = {};
    float mrow[4], alpha[4];
#pragma unroll
    for (int r = 0; r < 4; ++r) mrow[r] = -INFINITY;

    for (int j = 0; j < ntiles; ++j) {
      int kv0 = j << 7;
      __syncthreads();  // LDS reuse vs previous tile/phase
      // stage K tile [128 kv][128 d]: 2048 chunks, swizzled
#pragma unroll
      for (int i = 0; i < 8; ++i) {
        int L = i * 256 + t;
        int row = L >> 4, sc = L & 15;
        int c = (sc & 8) | ((sc & 7) ^ (row & 7));
        gl_lds16(gK + (size_t)(kv0 + row) * 256 + c * 16, (char*)sK + L * 16);
      }
      // stage V tile [128 d][128 kv] from Vt: 2048 chunks, swizzled
#pragma unroll
      for (int i = 0; i < 8; ++i) {
        int L = i * 256 + t;
        int row = L >> 4, sc = L & 15;
        int c = (sc & 8) | ((sc & 7) ^ (row & 7));
        gl_lds16(gV + (size_t)row * 4096 + kv0 * 2 + c * 16, (char*)sV + L * 16);
      }
      asm volatile("s_waitcnt vmcnt(0)" ::: "memory");
      __syncthreads();

      // S = Q K^T, pre-scaled into log2 domain (16 q-rows x 128 kv-cols per wave)
      float sv[8][4];
#pragma unroll
      for (int nt = 0; nt < 8; ++nt) {
        f32x4 z = {};
#pragma unroll
        for (int kc = 0; kc < 4; ++kc) {
          int sc = ((kc & 2) << 2) | (((((kc & 1) << 2) | quad)) ^ (l16 & 7));
          bf16x8 bk = *(const bf16x8*)(sK + (nt * 16 + l16) * 128 + sc * 8);
          z = __builtin_amdgcn_mfma_f32_16x16x32_bf16(aq[kc], bk, z, 0, 0, 0);
        }
#pragma unroll
        for (int r = 0; r < 4; ++r) sv[nt][r] = z[r] * SCL;
      }
      if (j == ntiles - 1) {  // tile containing the diagonal: causal mask
#pragma unroll
        for (int nt = 0; nt < 8; ++nt) {
          int col = kv0 + nt * 16 + l16;
#pragma unroll
          for (int r = 0; r < 4; ++r) {
            int row = q0 + w * 16 + quad * 4 + r;
            if (col > row) sv[nt][r] = -1e9f;
          }
        }
      }
      // online softmax (max only; sum via ones-rows MFMA)
#pragma unroll
      for (int r = 0; r < 4; ++r) {
        float mx = sv[0][r];
#pragma unroll
        for (int nt = 1; nt < 8; ++nt) mx = fmaxf(mx, sv[nt][r]);
#pragma unroll
        for (int off = 1; off < 16; off <<= 1) mx = fmaxf(mx, __shfl_xor(mx, off, 64));
        float mnew = fmaxf(mrow[r], mx);
        alpha[r] = exp2f(mrow[r] - mnew);
        mrow[r] = mnew;
#pragma unroll
        for (int nt = 0; nt < 8; ++nt) sv[nt][r] = exp2f(sv[nt][r] - mnew);
      }
      // rescale accumulators once per tile
#pragma unroll
      for (int nt = 0; nt < 8; ++nt)
#pragma unroll
        for (int r = 0; r < 4; ++r) o[nt][r] *= alpha[r];
#pragma unroll
      for (int r = 0; r < 4; ++r) ol[r] *= alpha[r];

      // PV in two 64-kv halves through wave-private sP
#pragma unroll
      for (int half = 0; half < 2; ++half) {
#pragma unroll
        for (int nt = 0; nt < 4; ++nt)
#pragma unroll
          for (int r = 0; r < 4; ++r)
            sp[(quad * 4 + r) * 72 + nt * 16 + l16] = (__bf16)sv[half * 4 + nt][r];
        asm volatile("s_waitcnt lgkmcnt(0)" ::: "memory");  // writes visible (and prior reads landed)
#pragma unroll
        for (int kc = 0; kc < 2; ++kc) {
          bf16x8 ap = *(const bf16x8*)(sp + l16 * 72 + kc * 32 + quad * 8);
          int sc = (half << 3) | (((kc << 2) | quad) ^ (l16 & 7));
#pragma unroll
          for (int nt = 0; nt < 8; ++nt) {
            bf16x8 bv = *(const bf16x8*)(sV + (nt * 16 + l16) * 128 + sc * 8);
            o[nt] = __builtin_amdgcn_mfma_f32_16x16x32_bf16(ap, bv, o[nt], 0, 0, 0);
          }
          bf16x8 bv1 = *(const bf16x8*)(sV + (128 + l16) * 128 + sc * 8);  // ones
          ol = __builtin_amdgcn_mfma_f32_16x16x32_bf16(ap, bv1, ol, 0, 0, 0);
        }
        asm volatile("s_waitcnt lgkmcnt(0)" ::: "memory");  // reads landed before sP overwrite
      }
    }

    // epilogue: O/l -> attn buffer [b][s][h][d] bf16
#pragma unroll
    for (int r = 0; r < 4; ++r) {
      float inv = 1.f / ol[r];
      int srow = q0 + w * 16 + quad * 4 + r;
      __bf16* op = Ob + ((size_t)((b * 2048 + srow) * 16 + h)) * 128;
#pragma unroll
      for (int nt = 0; nt < 8; ++nt)
        op[nt * 16 + l16] = (__bf16)(o[nt][r] * inv);
    }
  }
}

extern "C" void kernel_launch(void* const* d_in, const int* in_sizes, int n_in,
                              void* d_out, int out_size, void* d_ws, size_t ws_size,
                              hipStream_t stream) {
  const float* hs   = (const float*)d_in[0];
  const float* wqkv = (const float*)d_in[2];
  const float* bqkv = (const float*)d_in[3];
  const float* wout = (const float*)d_in[4];
  const float* bout = (const float*)d_in[5];
  float* out = (float*)d_out;

  char* ws = (char*)d_ws;
  __bf16* hsb   = (__bf16*)(ws);                // [4096][2048]; reused as attnb
  __bf16* attnb = (__bf16*)(ws);
  __bf16* wqkvT = (__bf16*)(ws + 16777216);     // [6144][2048], rows reordered [which][h][128]
  __bf16* woutT = (__bf16*)(ws + 41943040);     // [2048][2048]
  __bf16* Qb    = (__bf16*)(ws + 50331648);     // [32][2048][128]
  __bf16* Kb    = (__bf16*)(ws + 67108864);     // [32][2048][128]
  __bf16* Vt    = (__bf16*)(ws + 83886080);     // [32][128][2048] (transposed V)
  // total ws use: 100,663,296 B

  k_cast<<<8192, 256, 0, stream>>>(hs, hsb, 2097152);
  k_transpose2<<<dim3(256, 64), 256, 0, stream>>>(wqkv, wqkvT, wout, woutT);
  k_gemm_qkv<<<dim3(24, 32), 512, 0, stream>>>(hsb, wqkvT, bqkv, Qb, Kb, Vt);
  k_attn<<<dim3(16, 32), 256, 0, stream>>>(Qb, Kb, Vt, attnb);
  k_gemm_out<<<dim3(8, 32), 512, 0, stream>>>(attnb, woutT, bout, out);
}

// Round 15
// 370.251 us; speedup vs baseline: 1.1462x; 1.0480x over previous
//
#include <hip/hip_runtime.h>
#include <stdint.h>
#include <math.h>

typedef float  f32x4  __attribute__((ext_vector_type(4)));
typedef __bf16 bf16x8 __attribute__((ext_vector_type(8)));
typedef __bf16 bf16x4 __attribute__((ext_vector_type(4)));

// async global->LDS, 16B per lane. LDS side must be wave-uniform base + lane*16.
__device__ __forceinline__ void gl_lds16(const void* g, void* l) {
  __builtin_amdgcn_global_load_lds(
      (__attribute__((address_space(1))) void*)(uintptr_t)g,
      (__attribute__((address_space(3))) void*)l, 16, 0, 0);
}

// ---------------- cast fp32 -> bf16, x4 vectorized ----------------
__global__ __launch_bounds__(256) void k_cast(const float* __restrict__ in,
                                              __bf16* __restrict__ out, int n4) {
  int i = blockIdx.x * 256 + threadIdx.x;
  if (i >= n4) return;
  f32x4 v = ((const f32x4*)in)[i];
  ((bf16x4*)out)[i] = __builtin_convertvector(v, bf16x4);
}

// ---------------- both weight transposes in one kernel ----------------
// QKV weight rows are reordered on output: original col n = h*384 + which*128 + d
// -> row n' = which*2048 + h*128 + d, so 256-wide GEMM n-tiles are pure Q/K/V.
__global__ __launch_bounds__(256) void k_transpose2(const float* __restrict__ inA,
                                                    __bf16* __restrict__ outA,
                                                    const float* __restrict__ inB,
                                                    __bf16* __restrict__ outB) {
  __shared__ float tile[32][33];
  int bx = blockIdx.x;
  const float* in; __bf16* out; int N, n0, nout;
  if (bx < 192) {
    in = inA; out = outA; N = 6144; n0 = bx * 32;
    int h = n0 / 384, rr = n0 - h * 384;
    int which = rr >> 7, d0 = rr & 127;     // 32-row block never crosses a 128-boundary
    nout = which * 2048 + h * 128 + d0;
  } else {
    in = inB; out = outB; N = 2048; n0 = (bx - 192) * 32; nout = n0;
  }
  const int K = 2048;
  int k0 = blockIdx.y * 32;
  int tx = threadIdx.x & 31, ty = threadIdx.x >> 5;
#pragma unroll
  for (int i = 0; i < 32; i += 8)
    tile[ty + i][tx] = in[(size_t)(k0 + ty + i) * N + n0 + tx];
  __syncthreads();
#pragma unroll
  for (int i = 0; i < 32; i += 8)
    out[(size_t)(nout + ty + i) * K + k0 + tx] = (__bf16)tile[tx][ty + i];
}

// ---------------- shared GEMM core: BM=128 x BN=256, BK=64, 8 waves ----------------
// 3-slot LDS ring, counted vmcnt(6), raw s_barrier, fragment-register
// double-buffering (ds_reads for phase p+1 issue before the MFMAs of phase p).
__device__ __forceinline__ void gemm_core(
    const char* gA, const char* gB, __bf16* smem,
    int wr, int wc, int quad, int l16, int x7, int tthr,
    f32x4 acc[4][4]) {
  int srcA[2], ldsA[2], srcB[4], ldsB[4];
#pragma unroll
  for (int i = 0; i < 2; ++i) {
    int L = i * 512 + tthr;
    int row = L >> 3, sc = L & 7, c = sc ^ (row & 7);
    srcA[i] = row * 4096 + c * 16; ldsA[i] = L * 16;
  }
#pragma unroll
  for (int i = 0; i < 4; ++i) {
    int L = i * 512 + tthr;
    int row = L >> 3, sc = L & 7, c = sc ^ (row & 7);
    srcB[i] = row * 4096 + c * 16; ldsB[i] = L * 16;
  }

  // prologue: stage K-tiles 0 and 1 (6 loads/thread each)
#pragma unroll
  for (int tt = 0; tt < 2; ++tt) {
    int kb = tt * 128;
    char* lA = (char*)smem + tt * 49152;
    char* lB = lA + 16384;
    gl_lds16(gA + srcA[0] + kb, lA + ldsA[0]);
    gl_lds16(gA + srcA[1] + kb, lA + ldsA[1]);
#pragma unroll
    for (int i = 0; i < 4; ++i) gl_lds16(gB + srcB[i] + kb, lB + ldsB[i]);
  }
  asm volatile("s_waitcnt vmcnt(6)" ::: "memory");   // own tile-0 loads landed
  __builtin_amdgcn_s_barrier();                       // all waves' tile-0 landed

  int cs0 = (quad ^ x7) * 8;          // k-slot 0 column select
  int cs1 = ((4 | quad) ^ x7) * 8;    // k-slot 1 column select
  int rowA = (wr * 64 + l16) * 64;    // frag row bases (elems)
  int rowB = (wc * 64 + l16) * 64;

  bf16x8 afA[4], bfA[4], afB[4], bfB[4];
  // preload frags for tile 0, k-slot 0
#pragma unroll
  for (int mt = 0; mt < 4; ++mt) afA[mt] = *(const bf16x8*)(smem + rowA + mt * 1024 + cs0);
#pragma unroll
  for (int nt = 0; nt < 4; ++nt) bfA[nt] = *(const bf16x8*)(smem + 8192 + rowB + nt * 1024 + cs0);

  int slot = 0;
  for (int t = 0; t < 32; ++t) {
    int slot1 = slot + 1; if (slot1 >= 3) slot1 -= 3;
    int slot2 = slot + 2; if (slot2 >= 3) slot2 -= 3;
    const __bf16* sAs  = smem + slot * 24576;
    const __bf16* sBs  = sAs + 8192;
    const __bf16* sAs1 = smem + slot1 * 24576;
    const __bf16* sBs1 = sAs1 + 8192;
    char* lA = (char*)smem + slot2 * 49152;
    char* lB = lA + 16384;
    int kb = (t + 2) * 128;
    bool pf = (t < 30);

    // ---- phase k=0: prefetch k=1 frags, stage group 0, MFMA k=0 ----
    if (pf) {
      gl_lds16(gA + srcA[0] + kb, lA + ldsA[0]);
      gl_lds16(gA + srcA[1] + kb, lA + ldsA[1]);
      gl_lds16(gB + srcB[0] + kb, lB + ldsB[0]);
    }
#pragma unroll
    for (int mt = 0; mt < 4; ++mt) afB[mt] = *(const bf16x8*)(sAs + rowA + mt * 1024 + cs1);
#pragma unroll
    for (int nt = 0; nt < 4; ++nt) bfB[nt] = *(const bf16x8*)(sBs + rowB + nt * 1024 + cs1);
    __builtin_amdgcn_s_setprio(1);
#pragma unroll
    for (int mt = 0; mt < 4; ++mt)
#pragma unroll
      for (int nt = 0; nt < 4; ++nt)
        acc[mt][nt] = __builtin_amdgcn_mfma_f32_16x16x32_bf16(afA[mt], bfA[nt], acc[mt][nt], 0, 0, 0);
    __builtin_amdgcn_s_setprio(0);

    // ---- phase k=1: stage group 1, vmcnt+barrier, prefetch next-tile k=0 frags, MFMA k=1 ----
    if (pf) {
      gl_lds16(gB + srcB[1] + kb, lB + ldsB[1]);
      gl_lds16(gB + srcB[2] + kb, lB + ldsB[2]);
      gl_lds16(gB + srcB[3] + kb, lB + ldsB[3]);
    }
    if (pf) asm volatile("s_waitcnt vmcnt(6)" ::: "memory");   // tile t+1 fully landed (own)
    else    asm volatile("s_waitcnt vmcnt(0)" ::: "memory");   // pipeline drain
    __builtin_amdgcn_s_barrier();                               // all waves: t+1 landed; t-1 reads done
    if (t < 31) {
#pragma unroll
      for (int mt = 0; mt < 4; ++mt) afA[mt] = *(const bf16x8*)(sAs1 + rowA + mt * 1024 + cs0);
#pragma unroll
      for (int nt = 0; nt < 4; ++nt) bfA[nt] = *(const bf16x8*)(sBs1 + rowB + nt * 1024 + cs0);
    }
    __builtin_amdgcn_s_setprio(1);
#pragma unroll
    for (int mt = 0; mt < 4; ++mt)
#pragma unroll
      for (int nt = 0; nt < 4; ++nt)
        acc[mt][nt] = __builtin_amdgcn_mfma_f32_16x16x32_bf16(afB[mt], bfB[nt], acc[mt][nt], 0, 0, 0);
    __builtin_amdgcn_s_setprio(0);
    __builtin_amdgcn_s_barrier();   // tile boundary: protects slot recycle for staging
    slot = slot1;
  }
}

// ---------------- QKV GEMM + fused RoPE + fused V-transpose ----------------
// n-tiles are 256 wide over reordered weights: which = bx>>3; each wave's 64
// n-cols sit inside one head (h = (bx&7)*2 + (wc>>1), d = (wc&1)*64 + ...).
// XCD-aware decode (best-measured): each XCD owns a 4-row by-band.
__global__ __launch_bounds__(512, 2) void k_gemm_qkv(
    const __bf16* __restrict__ A, const __bf16* __restrict__ Bt,
    const float* __restrict__ bias,
    __bf16* __restrict__ Qo, __bf16* __restrict__ Ko, __bf16* __restrict__ Vt) {
  __shared__ __bf16 smem[3 * 24576];   // 147456 B
  int t = threadIdx.x;
  int w = t >> 6, lane = t & 63;
  int wr = w >> 2, wc = w & 3;
  int quad = lane >> 4, l16 = lane & 15, x7 = lane & 7;

  int g = (int)blockIdx.x + (int)blockIdx.y * 24;   // 0..767, x-fastest dispatch
  int xcd = g & 7, idx = g >> 3;                    // idx 0..95
  int by = (xcd << 2) | (idx & 3);                  // 4-row band per XCD
  int bx = idx >> 2;                                // 0..23, advances every 4 blocks
  int m0 = by << 7;
  int n0 = bx << 8;

  f32x4 acc[4][4] = {};
  const char* gA = (const char*)(A + (size_t)m0 * 2048);
  const char* gB = (const char*)(Bt + (size_t)n0 * 2048);
  gemm_core(gA, gB, smem, wr, wc, quad, l16, x7, t, acc);

  int which = bx >> 3;
  int h = ((bx & 7) << 1) + (wc >> 1);
  int dbase = (wc & 1) << 6;
  int b2 = m0 >> 11, sbase = m0 & 2047;
  size_t bh = (size_t)(b2 * 16 + h);

  if (which == 2) {
    // V: per-wave LDS transpose (64 d x 64 s, stride 72 for 16B-aligned reads),
    // coalesced 16B stores into Vt [bh][128][2048]. Last core barrier precedes this.
    __bf16* sp = smem + w * 4608;      // 64*72 elems per wave
    const float* bptr = bias + h * 384 + 256 + dbase;
#pragma unroll
    for (int nt = 0; nt < 4; ++nt) {
      float bz = bptr[nt * 16 + l16];
#pragma unroll
      for (int mt = 0; mt < 4; ++mt) {
        bf16x4 v;
#pragma unroll
        for (int r = 0; r < 4; ++r) v[r] = (__bf16)(acc[mt][nt][r] + bz);
        *(bf16x4*)(sp + (nt * 16 + l16) * 72 + mt * 16 + quad * 4) = v;
      }
    }
    asm volatile("s_waitcnt lgkmcnt(0)" ::: "memory");
    int dl = lane >> 3, sseg = lane & 7;
#pragma unroll
    for (int p = 0; p < 8; ++p) {
      int d_local = p * 8 + dl;
      bf16x8 v = *(const bf16x8*)(sp + d_local * 72 + sseg * 8);
      *(bf16x8*)(Vt + (bh * 128 + dbase + d_local) * 2048 + sbase + wr * 64 + sseg * 8) = v;
    }
  } else {
    __bf16* dst = which ? Ko : Qo;
    const float* bptr = bias + h * 384 + which * 128 + dbase;
    float invf = exp2f(-(float)l16 * 0.83048202372184058f);  // 10000^(-l16/16)
#pragma unroll
    for (int mt = 0; mt < 4; ++mt) {
      int m = m0 + wr * 64 + mt * 16 + quad * 4;
#pragma unroll
      for (int nt = 0; nt < 4; ++nt) {
        int d = dbase + nt * 16 + l16;
        float bz = bptr[nt * 16 + l16];
        if (dbase == 0 && nt < 2) {
          if (nt == 0) {  // RoPE pair: this lane holds d=l16 and d=l16+16
            float bz1 = bptr[16 + l16];
#pragma unroll
            for (int r = 0; r < 4; ++r) {
              int s = (m + r) & 2047;
              float sn, cs2;
              __sincosf((float)s * invf, &sn, &cs2);
              float x1 = acc[mt][0][r] + bz;
              float x2 = acc[mt][1][r] + bz1;
              size_t off = (bh * 2048 + s) << 7;
              dst[off + l16]      = (__bf16)(x1 * cs2 - x2 * sn);
              dst[off + 16 + l16] = (__bf16)(x2 * cs2 + x1 * sn);
            }
          }
        } else {
#pragma unroll
          for (int r = 0; r < 4; ++r) {
            int s = (m + r) & 2047;
            dst[(bh * 2048 + s) * 128 + d] = (__bf16)(acc[mt][nt][r] + bz);
          }
        }
      }
    }
  }
}

// ---------------- Out-proj GEMM: attn[4096][2048] bf16 x Bt[2048][2048] bf16 -> f32 ----------------
__global__ __launch_bounds__(512, 2) void k_gemm_out(
    const __bf16* __restrict__ A, const __bf16* __restrict__ Bt,
    const float* __restrict__ bias, float* __restrict__ Out) {
  __shared__ __bf16 smem[3 * 24576];
  int t = threadIdx.x;
  int w = t >> 6, lane = t & 63;
  int wr = w >> 2, wc = w & 3;
  int quad = lane >> 4, l16 = lane & 15, x7 = lane & 7;

  int g = (int)blockIdx.x + (int)blockIdx.y * 8;    // 0..255
  int xcd = g & 7, idx = g >> 3;                    // idx 0..31
  int by = (xcd << 2) | (idx & 3);                  // 4-row band per XCD
  int bx = idx >> 2;                                // 0..7
  int m0 = by << 7;
  int n0 = bx << 8;

  f32x4 acc[4][4] = {};
  const char* gA = (const char*)(A + (size_t)m0 * 2048);
  const char* gB = (const char*)(Bt + (size_t)n0 * 2048);
  gemm_core(gA, gB, smem, wr, wc, quad, l16, x7, t, acc);

#pragma unroll
  for (int mt = 0; mt < 4; ++mt) {
    int m = m0 + wr * 64 + mt * 16 + quad * 4;
#pragma unroll
    for (int nt = 0; nt < 4; ++nt) {
      int n = n0 + wc * 64 + nt * 16 + l16;
      float bz = bias[n];
#pragma unroll
      for (int r = 0; r < 4; ++r)
        Out[(size_t)(m + r) * 2048 + n] = acc[mt][nt][r] + bz;
    }
  }
}

// ---------------- causal flash attention, 128-row KV tiles ----------------
// NEW: head-affine XCD decode. Each XCD owns all 16 q-blocks of 4 heads
// (bh = xcd mod 8), so its concurrent blocks share a 4MB K/V set that fits
// its private L2 -> K/V fetched ~once per XCD instead of 8x (FETCH 255MB->~40MB).
__global__ __launch_bounds__(256) void k_attn(const __bf16* __restrict__ Qb,
                                              const __bf16* __restrict__ Kb,
                                              const __bf16* __restrict__ Vt,
                                              __bf16* __restrict__ Ob) {
  __shared__ __bf16 sK[128 * 128];   // [kv][d], swizzled 16B chunks (16/row)
  __shared__ __bf16 sV[144 * 128];   // [d][kv], swizzled; rows 128..143 = 1.0
  __shared__ __bf16 sP[4 * 16 * 72];
  const float SCL = 0.08838834764831845f * 1.4426950408889634f;  // 1/sqrt(128)*log2e
  int t = threadIdx.x, w = t >> 6, lane = t & 63;
  int quad = lane >> 4, l16 = lane & 15;

  int g = (int)blockIdx.x + (int)blockIdx.y * 16;  // 0..511, x-fastest dispatch
  int xcd = g & 7, idx = g >> 3;                   // idx 0..63
  int bh = xcd + ((idx & 3) << 3);                 // 4 heads per XCD (bh ≡ xcd mod 8)
  int bx0 = idx >> 2;                              // 0..15 q-tile pair index

  size_t base = (size_t)bh * (2048 * 128);
  const char* gK = (const char*)(Kb + base);
  const char* gV = (const char*)(Vt + base);
  __bf16* sp = sP + w * (16 * 72);
  int b = bh >> 4, h = bh & 15;

  // ones rows (sV rows 128..143), never touched by staging
  for (int i = t; i < 2048; i += 256) sV[128 * 128 + i] = (__bf16)1.0f;

  for (int ph = 0; ph < 2; ++ph) {
    int qt = (ph == 0) ? bx0 : 31 - bx0;
    int q0 = qt * 64;
    int ntiles = (qt >> 1) + 1;

    bf16x8 aq[4];
    {
      const __bf16* qp = Qb + base + (size_t)(q0 + w * 16 + l16) * 128 + quad * 8;
#pragma unroll
      for (int kc = 0; kc < 4; ++kc) aq[kc] = *(const bf16x8*)(qp + kc * 32);
    }

    f32x4 o[8] = {};
    f32x4 ol = {};
    float mrow[4], alpha[4];
#pragma unroll
    for (int r = 0; r < 4; ++r) mrow[r] = -INFINITY;

    for (int j = 0; j < ntiles; ++j) {
      int kv0 = j << 7;
      __syncthreads();  // LDS reuse vs previous tile/phase
      // stage K tile [128 kv][128 d]: 2048 chunks, swizzled
#pragma unroll
      for (int i = 0; i < 8; ++i) {
        int L = i * 256 + t;
        int row = L >> 4, sc = L & 15;
        int c = (sc & 8) | ((sc & 7) ^ (row & 7));
        gl_lds16(gK + (size_t)(kv0 + row) * 256 + c * 16, (char*)sK + L * 16);
      }
      // stage V tile [128 d][128 kv] from Vt: 2048 chunks, swizzled
#pragma unroll
      for (int i = 0; i < 8; ++i) {
        int L = i * 256 + t;
        int row = L >> 4, sc = L & 15;
        int c = (sc & 8) | ((sc & 7) ^ (row & 7));
        gl_lds16(gV + (size_t)row * 4096 + kv0 * 2 + c * 16, (char*)sV + L * 16);
      }
      asm volatile("s_waitcnt vmcnt(0)" ::: "memory");
      __syncthreads();

      // S = Q K^T, pre-scaled into log2 domain (16 q-rows x 128 kv-cols per wave)
      float sv[8][4];
#pragma unroll
      for (int nt = 0; nt < 8; ++nt) {
        f32x4 z = {};
#pragma unroll
        for (int kc = 0; kc < 4; ++kc) {
          int sc = ((kc & 2) << 2) | (((((kc & 1) << 2) | quad)) ^ (l16 & 7));
          bf16x8 bk = *(const bf16x8*)(sK + (nt * 16 + l16) * 128 + sc * 8);
          z = __builtin_amdgcn_mfma_f32_16x16x32_bf16(aq[kc], bk, z, 0, 0, 0);
        }
#pragma unroll
        for (int r = 0; r < 4; ++r) sv[nt][r] = z[r] * SCL;
      }
      if (j == ntiles - 1) {  // tile containing the diagonal: causal mask
#pragma unroll
        for (int nt = 0; nt < 8; ++nt) {
          int col = kv0 + nt * 16 + l16;
#pragma unroll
          for (int r = 0; r < 4; ++r) {
            int row = q0 + w * 16 + quad * 4 + r;
            if (col > row) sv[nt][r] = -1e9f;
          }
        }
      }
      // online softmax (max only; sum via ones-rows MFMA)
#pragma unroll
      for (int r = 0; r < 4; ++r) {
        float mx = sv[0][r];
#pragma unroll
        for (int nt = 1; nt < 8; ++nt) mx = fmaxf(mx, sv[nt][r]);
#pragma unroll
        for (int off = 1; off < 16; off <<= 1) mx = fmaxf(mx, __shfl_xor(mx, off, 64));
        float mnew = fmaxf(mrow[r], mx);
        alpha[r] = exp2f(mrow[r] - mnew);
        mrow[r] = mnew;
#pragma unroll
        for (int nt = 0; nt < 8; ++nt) sv[nt][r] = exp2f(sv[nt][r] - mnew);
      }
      // rescale accumulators once per tile
#pragma unroll
      for (int nt = 0; nt < 8; ++nt)
#pragma unroll
        for (int r = 0; r < 4; ++r) o[nt][r] *= alpha[r];
#pragma unroll
      for (int r = 0; r < 4; ++r) ol[r] *= alpha[r];

      // PV in two 64-kv halves through wave-private sP
#pragma unroll
      for (int half = 0; half < 2; ++half) {
#pragma unroll
        for (int nt = 0; nt < 4; ++nt)
#pragma unroll
          for (int r = 0; r < 4; ++r)
            sp[(quad * 4 + r) * 72 + nt * 16 + l16] = (__bf16)sv[half * 4 + nt][r];
        asm volatile("s_waitcnt lgkmcnt(0)" ::: "memory");  // writes visible (and prior reads landed)
#pragma unroll
        for (int kc = 0; kc < 2; ++kc) {
          bf16x8 ap = *(const bf16x8*)(sp + l16 * 72 + kc * 32 + quad * 8);
          int sc = (half << 3) | (((kc << 2) | quad) ^ (l16 & 7));
#pragma unroll
          for (int nt = 0; nt < 8; ++nt) {
            bf16x8 bv = *(const bf16x8*)(sV + (nt * 16 + l16) * 128 + sc * 8);
            o[nt] = __builtin_amdgcn_mfma_f32_16x16x32_bf16(ap, bv, o[nt], 0, 0, 0);
          }
          bf16x8 bv1 = *(const bf16x8*)(sV + (128 + l16) * 128 + sc * 8);  // ones
          ol = __builtin_amdgcn_mfma_f32_16x16x32_bf16(ap, bv1, ol, 0, 0, 0);
        }
        asm volatile("s_waitcnt lgkmcnt(0)" ::: "memory");  // reads landed before sP overwrite
      }
    }

    // epilogue: O/l -> attn buffer [b][s][h][d] bf16
#pragma unroll
    for (int r = 0; r < 4; ++r) {
      float inv = 1.f / ol[r];
      int srow = q0 + w * 16 + quad * 4 + r;
      __bf16* op = Ob + ((size_t)((b * 2048 + srow) * 16 + h)) * 128;
#pragma unroll
      for (int nt = 0; nt < 8; ++nt)
        op[nt * 16 + l16] = (__bf16)(o[nt][r] * inv);
    }
  }
}

extern "C" void kernel_launch(void* const* d_in, const int* in_sizes, int n_in,
                              void* d_out, int out_size, void* d_ws, size_t ws_size,
                              hipStream_t stream) {
  const float* hs   = (const float*)d_in[0];
  const float* wqkv = (const float*)d_in[2];
  const float* bqkv = (const float*)d_in[3];
  const float* wout = (const float*)d_in[4];
  const float* bout = (const float*)d_in[5];
  float* out = (float*)d_out;

  char* ws = (char*)d_ws;
  __bf16* hsb   = (__bf16*)(ws);                // [4096][2048]; reused as attnb
  __bf16* attnb = (__bf16*)(ws);
  __bf16* wqkvT = (__bf16*)(ws + 16777216);     // [6144][2048], rows reordered [which][h][128]
  __bf16* woutT = (__bf16*)(ws + 41943040);     // [2048][2048]
  __bf16* Qb    = (__bf16*)(ws + 50331648);     // [32][2048][128]
  __bf16* Kb    = (__bf16*)(ws + 67108864);     // [32][2048][128]
  __bf16* Vt    = (__bf16*)(ws + 83886080);     // [32][128][2048] (transposed V)
  // total ws use: 100,663,296 B

  k_cast<<<8192, 256, 0, stream>>>(hs, hsb, 2097152);
  k_transpose2<<<dim3(256, 64), 256, 0, stream>>>(wqkv, wqkvT, wout, woutT);
  k_gemm_qkv<<<dim3(24, 32), 512, 0, stream>>>(hsb, wqkvT, bqkv, Qb, Kb, Vt);
  k_attn<<<dim3(16, 32), 256, 0, stream>>>(Qb, Kb, Vt, attnb);
  k_gemm_out<<<dim3(8, 32), 512, 0, stream>>>(attnb, woutT, bout, out);
}